// Round 10
// baseline (561.984 us; speedup 1.0000x reference)
//
#include <hip/hip_runtime.h>
#include <hip/hip_cooperative_groups.h>

namespace cg = cooperative_groups;

#define BS 2
#define HR 1024
#define WR 1024

static inline int cdiv(int a, int b) { return (a + b - 1) / b; }

// ---------------------------------------------------------------------------
// repack body:
//  - 7 conv layers:  w[oc][ic][ky][kx]  ->  wT[k][oc][ic]   (ic contiguous)
//  - fc1:            w[o][c*16+s]       ->  wT[o][s*64+c]   (NCHW->NHWC flatten)
__device__ __forceinline__ void repack_body(int idx,
        const float* s0, const float* s1, const float* s2, const float* s3,
        const float* s4, const float* s5, const float* s6,
        float* d0, float* d1, float* d2, float* d3, float* d4, float* d5, float* d6,
        const float* fcs, float* fcd) {
    const int CONV_TOTAL = 171648;
    if (idx < CONV_TOTAL) {
        const float* src[7] = {s0, s1, s2, s3, s4, s5, s6};
        float* dst[7]       = {d0, d1, d2, d3, d4, d5, d6};
        const int cout[7] = {16, 32, 64, 64, 64, 64, 64};
        const int cin[7]  = {8, 16, 32, 64, 64, 64, 64};
        const int sz[7]   = {1152, 4608, 18432, 36864, 36864, 36864, 36864};
        int l = 0, e = idx;
        while (e >= sz[l]) { e -= sz[l]; ++l; }
        int Cin = cin[l], Cout = cout[l];
        int oc = e / (Cin * 9);
        int rem = e - oc * Cin * 9;
        int ic = rem / 9;
        int k  = rem - ic * 9;
        dst[l][((size_t)(k * Cout + oc)) * Cin + ic] = src[l][e];
    } else {
        int e = idx - CONV_TOTAL;            // fc1: 262144 elements
        if (e >= 262144) return;
        int o = e >> 10, j = e & 1023;
        int s = j >> 6, c = j & 63;
        fcd[e] = fcs[(o << 10) + (c << 4) + s];
    }
}

// ll1: NCHW (2,3,256,256) s2 p1 -> NHWC (2,128,128,8)
__device__ __forceinline__ void ll1_body(int idx, const float* in, const float* w,
                                         const float* bias, float* out) {
    if (idx >= BS * 128 * 128) return;
    int ox = idx & 127;
    int oy = (idx >> 7) & 127;
    int b  = idx >> 14;

    float acc[8];
#pragma unroll
    for (int oc = 0; oc < 8; ++oc) acc[oc] = bias[oc];
#pragma unroll
    for (int ky = 0; ky < 3; ++ky) {
        int iy = 2 * oy - 1 + ky;
        if (iy < 0 || iy >= 256) continue;
#pragma unroll
        for (int kx = 0; kx < 3; ++kx) {
            int ix = 2 * ox - 1 + kx;
            if (ix < 0 || ix >= 256) continue;
#pragma unroll
            for (int ic = 0; ic < 3; ++ic) {
                float v = in[(((size_t)b * 3 + ic) * 256 + iy) * 256 + ix];
#pragma unroll
                for (int oc = 0; oc < 8; ++oc)
                    acc[oc] += w[oc * 27 + ic * 9 + ky * 3 + kx] * v;
            }
        }
    }
    float* op = out + (size_t)idx * 8;
#pragma unroll
    for (int oc = 0; oc < 8; ++oc) op[oc] = fmaxf(acc[oc], 0.0f);
}

// NHWC conv3x3 pad=1, G-way ic split. lane=(oc,icg); wT[k][oc][ic].
template <int COUT, int CIN, int G, bool RELU, bool HASBIAS>
__device__ __forceinline__ void conv_body(int idx, const float* in, const float* wT,
                                          const float* bias, float* out,
                                          int Hin, int Win, int Hout, int Wout, int stride) {
    constexpr int ICPG = CIN / G;
    int total = BS * Hout * Wout * COUT * G;
    if (idx >= total) return;
    int icg = idx & (G - 1);
    int oc  = (idx / G) & (COUT - 1);
    int pix = idx / (G * COUT);
    int ox = pix % Wout;
    int oy = (pix / Wout) % Hout;
    int b  = pix / (Wout * Hout);

    int iy0 = oy * stride - 1;
    int ix0 = ox * stride - 1;
    float acc = 0.0f;
#pragma unroll
    for (int ky = 0; ky < 3; ++ky) {
        int iy = iy0 + ky;
        if (iy < 0 || iy >= Hin) continue;
#pragma unroll
        for (int kx = 0; kx < 3; ++kx) {
            int ix = ix0 + kx;
            if (ix < 0 || ix >= Win) continue;
            int k = ky * 3 + kx;
            const float* wp = wT + ((size_t)(k * COUT + oc)) * CIN + icg * ICPG;
            const float* ip = in + ((size_t)((b * Hin + iy) * Win + ix)) * CIN + icg * ICPG;
#pragma unroll
            for (int ic4 = 0; ic4 < ICPG / 4; ++ic4) {
                float4 wv = *reinterpret_cast<const float4*>(wp + ic4 * 4);
                float4 iv = *reinterpret_cast<const float4*>(ip + ic4 * 4);
                acc += wv.x * iv.x + wv.y * iv.y + wv.z * iv.z + wv.w * iv.w;
            }
        }
    }
    if (G > 1) {
#pragma unroll
        for (int off = G / 2; off > 0; off >>= 1) acc += __shfl_xor(acc, off, 64);
    }
    if (icg == 0) {
        if (HASBIAS) acc += bias[oc];
        if (RELU) acc = fmaxf(acc, 0.0f);
        out[(size_t)pix * COUT + oc] = acc;
    }
}

// FC body, one 64-lane wave per output neuron. idx in [0, 64*BS*Out).
__device__ __forceinline__ void fc_body(int idx, const float* in, const float* w,
                                        const float* bias, float* out,
                                        int In, int Out, int do_relu) {
    int wid  = idx >> 6;
    int lane = idx & 63;
    if (wid >= BS * Out) return;
    int o = wid % Out;
    int b = wid / Out;
    const float* ip = in + (size_t)b * In;
    const float* wp = w + (size_t)o * In;

    float acc = 0.0f;
    for (int i = lane * 4; i < In; i += 64 * 4) {
        float4 wv = *reinterpret_cast<const float4*>(wp + i);
        float4 iv = *reinterpret_cast<const float4*>(ip + i);
        acc += wv.x * iv.x + wv.y * iv.y + wv.z * iv.z + wv.w * iv.w;
    }
#pragma unroll
    for (int off = 32; off > 0; off >>= 1) acc += __shfl_xor(acc, off, 64);
    if (lane == 0) {
        acc += bias[o];
        if (do_relu) acc = fmaxf(acc, 0.0f);
        out[(size_t)b * Out + o] = acc;
    }
}

// fuse_pred body: 16 lanes per output; idx in [0, BS*96*256*16).
__device__ __forceinline__ void fuse_body(int idx, const float* lf, const float* gfv,
                                          const float* pw, const float* pb, float* gt) {
    int gid  = idx >> 4;
    int lane = idx & 15;
    int total = BS * 96 * 256;
    if (gid >= total) return;
    int sp = gid % 256;
    int oc = (gid / 256) % 96;
    int b  = gid / (256 * 96);

    float4 lv = *reinterpret_cast<const float4*>(lf + ((size_t)(b * 256 + sp) * 64) + lane * 4);
    float4 gv = *reinterpret_cast<const float4*>(gfv + (size_t)b * 64 + lane * 4);
    float4 wv = *reinterpret_cast<const float4*>(pw + (size_t)oc * 64 + lane * 4);
    float fx0 = fmaxf(gv.x + lv.x, 0.0f);
    float fx1 = fmaxf(gv.y + lv.y, 0.0f);
    float fx2 = fmaxf(gv.z + lv.z, 0.0f);
    float fx3 = fmaxf(gv.w + lv.w, 0.0f);
    float acc = wv.x * fx0 + wv.y * fx1 + wv.z * fx2 + wv.w * fx3;
#pragma unroll
    for (int off = 8; off > 0; off >>= 1) acc += __shfl_xor(acc, off, 64);
    if (lane == 0) {
        int z = oc & 7, c12 = oc >> 3;         // pred ch = c12*8 + z
        int y = sp >> 4, x = sp & 15;
        gt[((size_t)b * 2048 + (size_t)(z * 16 + y) * 16 + x) * 12 + c12] = acc + pb[oc];
    }
}

// ---------------------------------------------------------------------------
struct CnnParams {
    // sources
    const float *low_res, *ll1w, *ll1b;
    const float *s0, *s1, *s2, *s3, *s4, *s5, *s6;   // ll2..gf2 weights
    const float *ll2b, *ll3b, *ll4b, *lf1b, *gf1b, *gf2b;
    const float *fc1w, *fc1b, *fc2w, *fc2b, *fc3w, *fc3b;
    const float *predw, *predb;
    // workspace
    float *wll2T, *wll3T, *wll4T, *wlf1T, *wlf2T, *wgf1T, *wgf2T, *wfc1T;
    float *b1, *b2, *b3, *b4, *lf1o, *lf2o, *gf1o, *gf2o;
    float *fc1o, *fc2o, *fc3o, *gt;
};

// One cooperative kernel for the whole low-res CNN; grid.sync between stages.
__global__ void __launch_bounds__(256, 2) cnn_coop(CnnParams p) {
    cg::grid_group grid = cg::this_grid();
    const int gtid = blockIdx.x * 256 + threadIdx.x;
    const int gstride = gridDim.x * 256;

    // S0: repack (433792) + ll1 (32768)
    for (int i = gtid; i < 433792 + 32768; i += gstride) {
        if (i < 433792)
            repack_body(i, p.s0, p.s1, p.s2, p.s3, p.s4, p.s5, p.s6,
                        p.wll2T, p.wll3T, p.wll4T, p.wlf1T, p.wlf2T, p.wgf1T, p.wgf2T,
                        p.fc1w, p.wfc1T);
        else
            ll1_body(i - 433792, p.low_res, p.ll1w, p.ll1b, p.b1);
    }
    grid.sync();
    // S1: ll2
    for (int i = gtid; i < BS*64*64*16; i += gstride)
        conv_body<16, 8, 1, true, true>(i, p.b1, p.wll2T, p.ll2b, p.b2, 128, 128, 64, 64, 2);
    grid.sync();
    // S2: ll3
    for (int i = gtid; i < BS*32*32*32; i += gstride)
        conv_body<32, 16, 1, true, true>(i, p.b2, p.wll3T, p.ll3b, p.b3, 64, 64, 32, 32, 2);
    grid.sync();
    // S3: ll4 (G=2)
    for (int i = gtid; i < BS*16*16*64*2; i += gstride)
        conv_body<64, 32, 2, true, true>(i, p.b3, p.wll4T, p.ll4b, p.b4, 32, 32, 16, 16, 2);
    grid.sync();
    // S4: lf1 (131072) + gf1 (32768), both G=4
    for (int i = gtid; i < 131072 + 32768; i += gstride) {
        if (i < 131072)
            conv_body<64, 64, 4, true, true>(i, p.b4, p.wlf1T, p.lf1b, p.lf1o, 16, 16, 16, 16, 1);
        else
            conv_body<64, 64, 4, true, true>(i - 131072, p.b4, p.wgf1T, p.gf1b, p.gf1o, 16, 16, 8, 8, 2);
    }
    grid.sync();
    // S5: lf2 (131072) + gf2 (8192), both G=4
    for (int i = gtid; i < 131072 + 8192; i += gstride) {
        if (i < 131072)
            conv_body<64, 64, 4, false, false>(i, p.lf1o, p.wlf2T, nullptr, p.lf2o, 16, 16, 16, 16, 1);
        else
            conv_body<64, 64, 4, true, true>(i - 131072, p.gf1o, p.wgf2T, p.gf2b, p.gf2o, 8, 8, 4, 4, 2);
    }
    grid.sync();
    // S6: fc1
    for (int i = gtid; i < BS*256*64; i += gstride)
        fc_body(i, p.gf2o, p.wfc1T, p.fc1b, p.fc1o, 1024, 256, 1);
    grid.sync();
    // S7: fc2
    for (int i = gtid; i < BS*128*64; i += gstride)
        fc_body(i, p.fc1o, p.fc2w, p.fc2b, p.fc2o, 256, 128, 1);
    grid.sync();
    // S8: fc3
    for (int i = gtid; i < BS*64*64; i += gstride)
        fc_body(i, p.fc2o, p.fc3w, p.fc3b, p.fc3o, 128, 64, 0);
    grid.sync();
    // S9: fuse_pred -> gt
    for (int i = gtid; i < BS*96*256*16; i += gstride)
        fuse_body(i, p.lf2o, p.fc3o, p.predw, p.predb, p.gt);
}

// ---------------------------------------------------------------------------
// Slice: one block per row; y-PRE-BLENDED slab (8z x 16x x 12c = 6KB).
__global__ void slice_row_kernel(const float* __restrict__ hr, const float* __restrict__ gt,
                                 const float* __restrict__ pw_mat, const float* __restrict__ pw_bias,
                                 const float* __restrict__ pw_bias_tag,
                                 const float* __restrict__ rho_a, const float* __restrict__ rho_t,
                                 float* __restrict__ out) {
    __shared__ float slab[1536];
    __shared__ float s_rt[48], s_ra[48], s_m[9], s_bt[3], s_pb;
    int t = threadIdx.x;
    int y = blockIdx.x & (HR - 1);
    int b = blockIdx.x >> 10;

    float gyv = (y + 0.5f) * (16.0f / HR);
    float fyf = fmaxf(floorf(gyv - 0.5f), 0.0f);
    float wyv = gyv - 0.5f - fyf;                 // keeps sign (torch semantics)
    int fy = (int)fyf; int cy = min(fy + 1, 15);
    float ey = 1.0f - wyv;

    if (t < 48) { s_rt[t] = rho_t[t]; s_ra[t] = rho_a[t]; }
    if (t < 9)  s_m[t] = pw_mat[t];
    if (t < 3)  s_bt[t] = pw_bias_tag[t];
    if (t == 0) s_pb = pw_bias[0];

    // stage y-blended slab: 384 f4
    const float* gb = gt + (size_t)b * 24576;
    for (int i = t; i < 384; i += 256) {
        int s = i * 4;
        int zz = s / 192;
        int rc = s - zz * 192;                    // x*12 + c
        float4 vf = *reinterpret_cast<const float4*>(gb + (size_t)(zz * 16 + fy) * 192 + rc);
        float4 vc = *reinterpret_cast<const float4*>(gb + (size_t)(zz * 16 + cy) * 192 + rc);
        float4 v;
        v.x = ey * vf.x + wyv * vc.x;
        v.y = ey * vf.y + wyv * vc.y;
        v.z = ey * vf.z + wyv * vc.z;
        v.w = ey * vf.w + wyv * vc.w;
        *reinterpret_cast<float4*>(slab + s) = v;
    }
    __syncthreads();

    const size_t plane = (size_t)HR * WR;
    int x0 = t * 4;
    const float* hp = hr + (size_t)b * 3 * plane + (size_t)y * WR + x0;
    float4 R4 = *reinterpret_cast<const float4*>(hp);
    float4 G4 = *reinterpret_cast<const float4*>(hp + plane);
    float4 B4 = *reinterpret_cast<const float4*>(hp + 2 * plane);
    float rr[4] = {R4.x, R4.y, R4.z, R4.w};
    float gg[4] = {G4.x, G4.y, G4.z, G4.w};
    float bb[4] = {B4.x, B4.y, B4.z, B4.w};

    float o0[4], o1[4], o2[4];
#pragma unroll
    for (int j = 0; j < 4; ++j) {
        int x = x0 + j;
        float r = rr[j], g = gg[j], bl = bb[j];

        float g0 = s_m[0] * r + s_m[1] * g + s_m[2] * bl + s_bt[0];
        float g1 = s_m[3] * r + s_m[4] * g + s_m[5] * bl + s_bt[1];
        float g2 = s_m[6] * r + s_m[7] * g + s_m[8] * bl + s_bt[2];
        float guide = s_pb;
#pragma unroll
        for (int k = 0; k < 16; ++k) {
            guide += fmaxf(g0 - s_rt[k * 3 + 0], 0.0f) * s_ra[k * 3 + 0];
            guide += fmaxf(g1 - s_rt[k * 3 + 1], 0.0f) * s_ra[k * 3 + 1];
            guide += fmaxf(g2 - s_rt[k * 3 + 2], 0.0f) * s_ra[k * 3 + 2];
        }

        float gx = (x + 0.5f) * (16.0f / WR);
        float gz = fminf(fmaxf(guide, 0.0f), 1.0f) * 8.0f;
        float fxf = fmaxf(floorf(gx - 0.5f), 0.0f);
        float fzf = fmaxf(floorf(gz - 0.5f), 0.0f);
        float wxv = gx - 0.5f - fxf;              // keeps sign
        float wzv = fabsf(gz - 0.5f - fzf);       // abs (torch semantics)
        int fx = (int)fxf; int cx = min(fx + 1, 15);
        int fz = (int)fzf; int cz = min(fz + 1, 7);
        float ex = 1.0f - wxv, ez = 1.0f - wzv;

        int o_f = fz * 192 + fx * 12;
        int o_c = cz * 192 + fx * 12;
        int dxo = (cx - fx) * 12;

        float w0 = ex * ez, w1 = ex * wzv, w2 = wxv * ez, w3 = wxv * wzv;

        float4 a0 = {0,0,0,0}, a1 = {0,0,0,0}, a2 = {0,0,0,0};
        const int offs[4] = {o_f, o_c, o_f + dxo, o_c + dxo};
        const float wts[4] = {w0, w1, w2, w3};
#pragma unroll
        for (int c = 0; c < 4; ++c) {
            const float* p = slab + offs[c];
            float4 v0 = *reinterpret_cast<const float4*>(p);
            float4 v1 = *reinterpret_cast<const float4*>(p + 4);
            float4 v2 = *reinterpret_cast<const float4*>(p + 8);
            float wv = wts[c];
            a0.x += wv * v0.x; a0.y += wv * v0.y; a0.z += wv * v0.z; a0.w += wv * v0.w;
            a1.x += wv * v1.x; a1.y += wv * v1.y; a1.z += wv * v1.z; a1.w += wv * v1.w;
            a2.x += wv * v2.x; a2.y += wv * v2.y; a2.z += wv * v2.z; a2.w += wv * v2.w;
        }
        o0[j] = a0.x * r + a0.y * g + a0.z * bl + a0.w;
        o1[j] = a1.x * r + a1.y * g + a1.z * bl + a1.w;
        o2[j] = a2.x * r + a2.y * g + a2.z * bl + a2.w;
    }

    float* op = out + (size_t)b * 3 * plane + (size_t)y * WR + x0;
    *reinterpret_cast<float4*>(op)              = make_float4(o0[0], o0[1], o0[2], o0[3]);
    *reinterpret_cast<float4*>(op + plane)      = make_float4(o1[0], o1[1], o1[2], o1[3]);
    *reinterpret_cast<float4*>(op + 2 * plane)  = make_float4(o2[0], o2[1], o2[2], o2[3]);
}

extern "C" void kernel_launch(void* const* d_in, const int* in_sizes, int n_in,
                              void* d_out, int out_size, void* d_ws, size_t ws_size,
                              hipStream_t stream) {
    const float* high_res   = (const float*)d_in[0];
    const float* low_res    = (const float*)d_in[1];
    const float* ll1_w = (const float*)d_in[2];  const float* ll1_b = (const float*)d_in[3];
    const float* ll2_w = (const float*)d_in[4];  const float* ll2_b = (const float*)d_in[5];
    const float* ll3_w = (const float*)d_in[6];  const float* ll3_b = (const float*)d_in[7];
    const float* ll4_w = (const float*)d_in[8];  const float* ll4_b = (const float*)d_in[9];
    const float* lf1_w = (const float*)d_in[10]; const float* lf1_b = (const float*)d_in[11];
    const float* lf2_w = (const float*)d_in[12];
    const float* gf1_w = (const float*)d_in[13]; const float* gf1_b = (const float*)d_in[14];
    const float* gf2_w = (const float*)d_in[15]; const float* gf2_b = (const float*)d_in[16];
    const float* fc1_w = (const float*)d_in[17]; const float* fc1_b = (const float*)d_in[18];
    const float* fc2_w = (const float*)d_in[19]; const float* fc2_b = (const float*)d_in[20];
    const float* fc3_w = (const float*)d_in[21]; const float* fc3_b = (const float*)d_in[22];
    const float* pred_w = (const float*)d_in[23]; const float* pred_b = (const float*)d_in[24];
    const float* pw_mat = (const float*)d_in[25];
    const float* pw_bias = (const float*)d_in[26];
    const float* pw_bias_tag = (const float*)d_in[27];
    const float* rho_a = (const float*)d_in[28];
    const float* rho_t = (const float*)d_in[29];

    float* ws = (float*)d_ws;
    // NHWC activations
    float* b1    = ws;                  // (2,128,128,8)  262144
    float* b2    = b1 + 262144;         // (2,64,64,16)   131072
    float* b3    = b2 + 131072;         // (2,32,32,32)    65536
    float* b4    = b3 + 65536;          // (2,16,16,64)    32768
    float* lf1o  = b4 + 32768;          // (2,16,16,64)    32768
    float* lf2o  = lf1o + 32768;        // (2,16,16,64)    32768
    float* gf1o  = lf2o + 32768;        // (2,8,8,64)       8192
    float* gf2o  = gf1o + 8192;         // (2,4,4,64)       2048
    float* fc1o  = gf2o + 2048;         // (2,256)           512
    float* fc2o  = fc1o + 512;          // (2,128)           256
    float* fc3o  = fc2o + 256;          // (2,64)            128
    float* gt    = fc3o + 128;          // (2,2048,12)     49152
    // repacked weights [k][oc][ic]
    float* wll2T = gt + 49152;          //  1152
    float* wll3T = wll2T + 1152;        //  4608
    float* wll4T = wll3T + 4608;        // 18432
    float* wlf1T = wll4T + 18432;       // 36864
    float* wlf2T = wlf1T + 36864;       // 36864
    float* wgf1T = wlf2T + 36864;       // 36864
    float* wgf2T = wgf1T + 36864;       // 36864
    float* wfc1T = wgf2T + 36864;       // 262144

    float* out = (float*)d_out;

    CnnParams P;
    P.low_res = low_res; P.ll1w = ll1_w; P.ll1b = ll1_b;
    P.s0 = ll2_w; P.s1 = ll3_w; P.s2 = ll4_w; P.s3 = lf1_w; P.s4 = lf2_w; P.s5 = gf1_w; P.s6 = gf2_w;
    P.ll2b = ll2_b; P.ll3b = ll3_b; P.ll4b = ll4_b; P.lf1b = lf1_b; P.gf1b = gf1_b; P.gf2b = gf2_b;
    P.fc1w = fc1_w; P.fc1b = fc1_b; P.fc2w = fc2_w; P.fc2b = fc2_b; P.fc3w = fc3_w; P.fc3b = fc3_b;
    P.predw = pred_w; P.predb = pred_b;
    P.wll2T = wll2T; P.wll3T = wll3T; P.wll4T = wll4T; P.wlf1T = wlf1T; P.wlf2T = wlf2T;
    P.wgf1T = wgf1T; P.wgf2T = wgf2T; P.wfc1T = wfc1T;
    P.b1 = b1; P.b2 = b2; P.b3 = b3; P.b4 = b4;
    P.lf1o = lf1o; P.lf2o = lf2o; P.gf1o = gf1o; P.gf2o = gf2o;
    P.fc1o = fc1o; P.fc2o = fc2o; P.fc3o = fc3o; P.gt = gt;

    // K1: entire low-res CNN as one cooperative kernel (512 blocks = 2/CU, co-resident)
    void* args[] = {(void*)&P};
    hipLaunchCooperativeKernel((const void*)cnn_coop, dim3(512), dim3(256), args, 0, stream);

    // K2: per-row slice (y-preblended slab)
    slice_row_kernel<<<BS*HR, dim3(256), 0, stream>>>(high_res, gt, pw_mat, pw_bias, pw_bias_tag,
                                                      rho_a, rho_t, out);
}

// Round 11
// 77.039 us; speedup vs baseline: 7.2948x; 7.2948x over previous
//
#include <hip/hip_runtime.h>

#define BS 2
#define HR 1024
#define WR 1024

static inline int cdiv(int a, int b) { return (a + b - 1) / b; }

// ---------------------------------------------------------------------------
// repack body:
//  - 7 conv layers:  w[oc][ic][ky][kx]  ->  wT[k][oc][ic]   (ic contiguous)
//  - fc1:            w[o][c*16+s]       ->  wT[o][s*64+c]   (NCHW->NHWC flatten)
__device__ __forceinline__ void repack_body(int idx,
        const float* s0, const float* s1, const float* s2, const float* s3,
        const float* s4, const float* s5, const float* s6,
        float* d0, float* d1, float* d2, float* d3, float* d4, float* d5, float* d6,
        const float* fcs, float* fcd) {
    const int CONV_TOTAL = 171648;
    if (idx < CONV_TOTAL) {
        const float* src[7] = {s0, s1, s2, s3, s4, s5, s6};
        float* dst[7]       = {d0, d1, d2, d3, d4, d5, d6};
        const int cout[7] = {16, 32, 64, 64, 64, 64, 64};
        const int cin[7]  = {8, 16, 32, 64, 64, 64, 64};
        const int sz[7]   = {1152, 4608, 18432, 36864, 36864, 36864, 36864};
        int l = 0, e = idx;
        while (e >= sz[l]) { e -= sz[l]; ++l; }
        int Cin = cin[l], Cout = cout[l];
        int oc = e / (Cin * 9);
        int rem = e - oc * Cin * 9;
        int ic = rem / 9;
        int k  = rem - ic * 9;
        dst[l][((size_t)(k * Cout + oc)) * Cin + ic] = src[l][e];
    } else {
        int e = idx - CONV_TOTAL;            // fc1: 262144 elements
        if (e >= 262144) return;
        int o = e >> 10, j = e & 1023;
        int s = j >> 6, c = j & 63;
        fcd[e] = fcs[(o << 10) + (c << 4) + s];
    }
}

// ll1: NCHW (2,3,256,256) s2 p1 -> NHWC (2,128,128,8)
__device__ __forceinline__ void ll1_body(int idx, const float* in, const float* w,
                                         const float* bias, float* out) {
    if (idx >= BS * 128 * 128) return;
    int ox = idx & 127;
    int oy = (idx >> 7) & 127;
    int b  = idx >> 14;

    float acc[8];
#pragma unroll
    for (int oc = 0; oc < 8; ++oc) acc[oc] = bias[oc];
#pragma unroll
    for (int ky = 0; ky < 3; ++ky) {
        int iy = 2 * oy - 1 + ky;
        if (iy < 0 || iy >= 256) continue;
#pragma unroll
        for (int kx = 0; kx < 3; ++kx) {
            int ix = 2 * ox - 1 + kx;
            if (ix < 0 || ix >= 256) continue;
#pragma unroll
            for (int ic = 0; ic < 3; ++ic) {
                float v = in[(((size_t)b * 3 + ic) * 256 + iy) * 256 + ix];
#pragma unroll
                for (int oc = 0; oc < 8; ++oc)
                    acc[oc] += w[oc * 27 + ic * 9 + ky * 3 + kx] * v;
            }
        }
    }
    float* op = out + (size_t)idx * 8;
#pragma unroll
    for (int oc = 0; oc < 8; ++oc) op[oc] = fmaxf(acc[oc], 0.0f);
}

// K1: repack (blocks [0,1695)) + ll1 (blocks [1695,1823))
__global__ void k1_repack_ll1(
        const float* s0, const float* s1, const float* s2, const float* s3,
        const float* s4, const float* s5, const float* s6,
        float* d0, float* d1, float* d2, float* d3, float* d4, float* d5, float* d6,
        const float* fcs, float* fcd,
        const float* lr, const float* ll1w, const float* ll1b, float* b1out) {
    int bid = blockIdx.x;
    if (bid < 1695)
        repack_body(bid * 256 + threadIdx.x, s0, s1, s2, s3, s4, s5, s6,
                    d0, d1, d2, d3, d4, d5, d6, fcs, fcd);
    else
        ll1_body((bid - 1695) * 256 + threadIdx.x, lr, ll1w, ll1b, b1out);
}

// ---------------------------------------------------------------------------
// NHWC conv3x3 pad=1, G-way ic split. lane=(oc,icg); wT[k][oc][ic].
template <int COUT, int CIN, int G, bool RELU, bool HASBIAS>
__device__ __forceinline__ void conv_body(int idx, const float* in, const float* wT,
                                          const float* bias, float* out,
                                          int Hin, int Win, int Hout, int Wout, int stride) {
    constexpr int ICPG = CIN / G;
    int total = BS * Hout * Wout * COUT * G;
    if (idx >= total) return;
    int icg = idx & (G - 1);
    int oc  = (idx / G) & (COUT - 1);
    int pix = idx / (G * COUT);
    int ox = pix % Wout;
    int oy = (pix / Wout) % Hout;
    int b  = pix / (Wout * Hout);

    int iy0 = oy * stride - 1;
    int ix0 = ox * stride - 1;
    float acc = 0.0f;
#pragma unroll
    for (int ky = 0; ky < 3; ++ky) {
        int iy = iy0 + ky;
        if (iy < 0 || iy >= Hin) continue;
#pragma unroll
        for (int kx = 0; kx < 3; ++kx) {
            int ix = ix0 + kx;
            if (ix < 0 || ix >= Win) continue;
            int k = ky * 3 + kx;
            const float* wp = wT + ((size_t)(k * COUT + oc)) * CIN + icg * ICPG;
            const float* ip = in + ((size_t)((b * Hin + iy) * Win + ix)) * CIN + icg * ICPG;
#pragma unroll
            for (int ic4 = 0; ic4 < ICPG / 4; ++ic4) {
                float4 wv = *reinterpret_cast<const float4*>(wp + ic4 * 4);
                float4 iv = *reinterpret_cast<const float4*>(ip + ic4 * 4);
                acc += wv.x * iv.x + wv.y * iv.y + wv.z * iv.z + wv.w * iv.w;
            }
        }
    }
    if (G > 1) {
#pragma unroll
        for (int off = G / 2; off > 0; off >>= 1) acc += __shfl_xor(acc, off, 64);
    }
    if (icg == 0) {
        if (HASBIAS) acc += bias[oc];
        if (RELU) acc = fmaxf(acc, 0.0f);
        out[(size_t)pix * COUT + oc] = acc;
    }
}

template <int COUT, int CIN, int G, bool RELU, bool HASBIAS>
__global__ void conv_nhwc_split(const float* __restrict__ in, const float* __restrict__ wT,
                                const float* __restrict__ bias, float* __restrict__ out,
                                int Hin, int Win, int Hout, int Wout, int stride) {
    conv_body<COUT, CIN, G, RELU, HASBIAS>(blockIdx.x * blockDim.x + threadIdx.x,
                                           in, wT, bias, out, Hin, Win, Hout, Wout, stride);
}

// K5: lf1 G=8 (blocks [0,1024)) + gf1 G=8 (blocks [1024,1280)), both read b4
__global__ void k5_lf1_gf1(const float* __restrict__ b4,
                           const float* __restrict__ wlf1T, const float* __restrict__ lf1b,
                           float* __restrict__ lf1o,
                           const float* __restrict__ wgf1T, const float* __restrict__ gf1b,
                           float* __restrict__ gf1o) {
    int bid = blockIdx.x;
    if (bid < 1024)
        conv_body<64, 64, 8, true, true>(bid * 256 + threadIdx.x, b4, wlf1T, lf1b, lf1o, 16, 16, 16, 16, 1);
    else
        conv_body<64, 64, 8, true, true>((bid - 1024) * 256 + threadIdx.x, b4, wgf1T, gf1b, gf1o, 16, 16, 8, 8, 2);
}

// K6: lf2 G=8 (blocks [0,1024)) + gf2 G=8 (blocks [1024,1088)), independent after K5
__global__ void k6_lf2_gf2(const float* __restrict__ lf1o,
                           const float* __restrict__ wlf2T, float* __restrict__ lf2o,
                           const float* __restrict__ gf1o,
                           const float* __restrict__ wgf2T, const float* __restrict__ gf2b,
                           float* __restrict__ gf2o) {
    int bid = blockIdx.x;
    if (bid < 1024)
        conv_body<64, 64, 8, false, false>(bid * 256 + threadIdx.x, lf1o, wlf2T, nullptr, lf2o, 16, 16, 16, 16, 1);
    else
        conv_body<64, 64, 8, true, true>((bid - 1024) * 256 + threadIdx.x, gf1o, wgf2T, gf2b, gf2o, 8, 8, 4, 4, 2);
}

// ---------------------------------------------------------------------------
// Fully-connected, one 64-lane wave per output neuron (chip-wide weight fetch).
__global__ void fc_wave_kernel(const float* __restrict__ in, const float* __restrict__ w,
                               const float* __restrict__ bias, float* __restrict__ out,
                               int In, int Out, int do_relu) {
    int wid  = (blockIdx.x * blockDim.x + threadIdx.x) >> 6;
    int lane = threadIdx.x & 63;
    if (wid >= BS * Out) return;
    int o = wid % Out;
    int b = wid / Out;
    const float* ip = in + (size_t)b * In;
    const float* wp = w + (size_t)o * In;

    float acc = 0.0f;
    for (int i = lane * 4; i < In; i += 64 * 4) {
        float4 wv = *reinterpret_cast<const float4*>(wp + i);
        float4 iv = *reinterpret_cast<const float4*>(ip + i);
        acc += wv.x * iv.x + wv.y * iv.y + wv.z * iv.z + wv.w * iv.w;
    }
#pragma unroll
    for (int off = 32; off > 0; off >>= 1) acc += __shfl_xor(acc, off, 64);
    if (lane == 0) {
        acc += bias[o];
        if (do_relu) acc = fmaxf(acc, 0.0f);
        out[(size_t)b * Out + o] = acc;
    }
}

// ---------------------------------------------------------------------------
// fusion = relu(gf + lf_nhwc); 1x1 conv -> channel-interleaved gt[b][z][y][x][12]
__global__ void fuse_pred_kernel(const float* __restrict__ lf, const float* __restrict__ gfv,
                                 const float* __restrict__ pw, const float* __restrict__ pb,
                                 float* __restrict__ gt) {
    int idx  = blockIdx.x * blockDim.x + threadIdx.x;
    int gid  = idx >> 4;                       // 16 lanes per output
    int lane = idx & 15;
    int total = BS * 96 * 256;
    if (gid >= total) return;
    int sp = gid % 256;
    int oc = (gid / 256) % 96;
    int b  = gid / (256 * 96);

    float4 lv = *reinterpret_cast<const float4*>(lf + ((size_t)(b * 256 + sp) * 64) + lane * 4);
    float4 gv = *reinterpret_cast<const float4*>(gfv + (size_t)b * 64 + lane * 4);
    float4 wv = *reinterpret_cast<const float4*>(pw + (size_t)oc * 64 + lane * 4);
    float fx0 = fmaxf(gv.x + lv.x, 0.0f);
    float fx1 = fmaxf(gv.y + lv.y, 0.0f);
    float fx2 = fmaxf(gv.z + lv.z, 0.0f);
    float fx3 = fmaxf(gv.w + lv.w, 0.0f);
    float acc = wv.x * fx0 + wv.y * fx1 + wv.z * fx2 + wv.w * fx3;
#pragma unroll
    for (int off = 8; off > 0; off >>= 1) acc += __shfl_xor(acc, off, 64);
    if (lane == 0) {
        int z = oc & 7, c12 = oc >> 3;         // pred ch = c12*8 + z
        int y = sp >> 4, x = sp & 15;
        gt[((size_t)b * 2048 + (size_t)(z * 16 + y) * 16 + x) * 12 + c12] = acc + pb[oc];
    }
}

// ---------------------------------------------------------------------------
// Slice: one block per row; y-PRE-BLENDED slab (8z x 16x x 12c = 6KB).
__global__ void slice_row_kernel(const float* __restrict__ hr, const float* __restrict__ gt,
                                 const float* __restrict__ pw_mat, const float* __restrict__ pw_bias,
                                 const float* __restrict__ pw_bias_tag,
                                 const float* __restrict__ rho_a, const float* __restrict__ rho_t,
                                 float* __restrict__ out) {
    __shared__ float slab[1536];
    __shared__ float s_rt[48], s_ra[48], s_m[9], s_bt[3], s_pb;
    int t = threadIdx.x;
    int y = blockIdx.x & (HR - 1);
    int b = blockIdx.x >> 10;

    float gyv = (y + 0.5f) * (16.0f / HR);
    float fyf = fmaxf(floorf(gyv - 0.5f), 0.0f);
    float wyv = gyv - 0.5f - fyf;                 // keeps sign (torch semantics)
    int fy = (int)fyf; int cy = min(fy + 1, 15);
    float ey = 1.0f - wyv;

    if (t < 48) { s_rt[t] = rho_t[t]; s_ra[t] = rho_a[t]; }
    if (t < 9)  s_m[t] = pw_mat[t];
    if (t < 3)  s_bt[t] = pw_bias_tag[t];
    if (t == 0) s_pb = pw_bias[0];

    // stage y-blended slab: 384 f4
    const float* gb = gt + (size_t)b * 24576;
    for (int i = t; i < 384; i += 256) {
        int s = i * 4;
        int zz = s / 192;
        int rc = s - zz * 192;                    // x*12 + c
        float4 vf = *reinterpret_cast<const float4*>(gb + (size_t)(zz * 16 + fy) * 192 + rc);
        float4 vc = *reinterpret_cast<const float4*>(gb + (size_t)(zz * 16 + cy) * 192 + rc);
        float4 v;
        v.x = ey * vf.x + wyv * vc.x;
        v.y = ey * vf.y + wyv * vc.y;
        v.z = ey * vf.z + wyv * vc.z;
        v.w = ey * vf.w + wyv * vc.w;
        *reinterpret_cast<float4*>(slab + s) = v;
    }
    __syncthreads();

    const size_t plane = (size_t)HR * WR;
    int x0 = t * 4;
    const float* hp = hr + (size_t)b * 3 * plane + (size_t)y * WR + x0;
    float4 R4 = *reinterpret_cast<const float4*>(hp);
    float4 G4 = *reinterpret_cast<const float4*>(hp + plane);
    float4 B4 = *reinterpret_cast<const float4*>(hp + 2 * plane);
    float rr[4] = {R4.x, R4.y, R4.z, R4.w};
    float gg[4] = {G4.x, G4.y, G4.z, G4.w};
    float bb[4] = {B4.x, B4.y, B4.z, B4.w};

    float o0[4], o1[4], o2[4];
#pragma unroll
    for (int j = 0; j < 4; ++j) {
        int x = x0 + j;
        float r = rr[j], g = gg[j], bl = bb[j];

        float g0 = s_m[0] * r + s_m[1] * g + s_m[2] * bl + s_bt[0];
        float g1 = s_m[3] * r + s_m[4] * g + s_m[5] * bl + s_bt[1];
        float g2 = s_m[6] * r + s_m[7] * g + s_m[8] * bl + s_bt[2];
        float guide = s_pb;
#pragma unroll
        for (int k = 0; k < 16; ++k) {
            guide += fmaxf(g0 - s_rt[k * 3 + 0], 0.0f) * s_ra[k * 3 + 0];
            guide += fmaxf(g1 - s_rt[k * 3 + 1], 0.0f) * s_ra[k * 3 + 1];
            guide += fmaxf(g2 - s_rt[k * 3 + 2], 0.0f) * s_ra[k * 3 + 2];
        }

        float gx = (x + 0.5f) * (16.0f / WR);
        float gz = fminf(fmaxf(guide, 0.0f), 1.0f) * 8.0f;
        float fxf = fmaxf(floorf(gx - 0.5f), 0.0f);
        float fzf = fmaxf(floorf(gz - 0.5f), 0.0f);
        float wxv = gx - 0.5f - fxf;              // keeps sign
        float wzv = fabsf(gz - 0.5f - fzf);       // abs (torch semantics)
        int fx = (int)fxf; int cx = min(fx + 1, 15);
        int fz = (int)fzf; int cz = min(fz + 1, 7);
        float ex = 1.0f - wxv, ez = 1.0f - wzv;

        int o_f = fz * 192 + fx * 12;
        int o_c = cz * 192 + fx * 12;
        int dxo = (cx - fx) * 12;

        float w0 = ex * ez, w1 = ex * wzv, w2 = wxv * ez, w3 = wxv * wzv;

        float4 a0 = {0,0,0,0}, a1 = {0,0,0,0}, a2 = {0,0,0,0};
        const int offs[4] = {o_f, o_c, o_f + dxo, o_c + dxo};
        const float wts[4] = {w0, w1, w2, w3};
#pragma unroll
        for (int c = 0; c < 4; ++c) {
            const float* p = slab + offs[c];
            float4 v0 = *reinterpret_cast<const float4*>(p);
            float4 v1 = *reinterpret_cast<const float4*>(p + 4);
            float4 v2 = *reinterpret_cast<const float4*>(p + 8);
            float wv = wts[c];
            a0.x += wv * v0.x; a0.y += wv * v0.y; a0.z += wv * v0.z; a0.w += wv * v0.w;
            a1.x += wv * v1.x; a1.y += wv * v1.y; a1.z += wv * v1.z; a1.w += wv * v1.w;
            a2.x += wv * v2.x; a2.y += wv * v2.y; a2.z += wv * v2.z; a2.w += wv * v2.w;
        }
        o0[j] = a0.x * r + a0.y * g + a0.z * bl + a0.w;
        o1[j] = a1.x * r + a1.y * g + a1.z * bl + a1.w;
        o2[j] = a2.x * r + a2.y * g + a2.z * bl + a2.w;
    }

    float* op = out + (size_t)b * 3 * plane + (size_t)y * WR + x0;
    *reinterpret_cast<float4*>(op)              = make_float4(o0[0], o0[1], o0[2], o0[3]);
    *reinterpret_cast<float4*>(op + plane)      = make_float4(o1[0], o1[1], o1[2], o1[3]);
    *reinterpret_cast<float4*>(op + 2 * plane)  = make_float4(o2[0], o2[1], o2[2], o2[3]);
}

extern "C" void kernel_launch(void* const* d_in, const int* in_sizes, int n_in,
                              void* d_out, int out_size, void* d_ws, size_t ws_size,
                              hipStream_t stream) {
    const float* high_res   = (const float*)d_in[0];
    const float* low_res    = (const float*)d_in[1];
    const float* ll1_w = (const float*)d_in[2];  const float* ll1_b = (const float*)d_in[3];
    const float* ll2_w = (const float*)d_in[4];  const float* ll2_b = (const float*)d_in[5];
    const float* ll3_w = (const float*)d_in[6];  const float* ll3_b = (const float*)d_in[7];
    const float* ll4_w = (const float*)d_in[8];  const float* ll4_b = (const float*)d_in[9];
    const float* lf1_w = (const float*)d_in[10]; const float* lf1_b = (const float*)d_in[11];
    const float* lf2_w = (const float*)d_in[12];
    const float* gf1_w = (const float*)d_in[13]; const float* gf1_b = (const float*)d_in[14];
    const float* gf2_w = (const float*)d_in[15]; const float* gf2_b = (const float*)d_in[16];
    const float* fc1_w = (const float*)d_in[17]; const float* fc1_b = (const float*)d_in[18];
    const float* fc2_w = (const float*)d_in[19]; const float* fc2_b = (const float*)d_in[20];
    const float* fc3_w = (const float*)d_in[21]; const float* fc3_b = (const float*)d_in[22];
    const float* pred_w = (const float*)d_in[23]; const float* pred_b = (const float*)d_in[24];
    const float* pw_mat = (const float*)d_in[25];
    const float* pw_bias = (const float*)d_in[26];
    const float* pw_bias_tag = (const float*)d_in[27];
    const float* rho_a = (const float*)d_in[28];
    const float* rho_t = (const float*)d_in[29];

    float* ws = (float*)d_ws;
    // NHWC activations
    float* b1    = ws;                  // (2,128,128,8)  262144
    float* b2    = b1 + 262144;         // (2,64,64,16)   131072
    float* b3    = b2 + 131072;         // (2,32,32,32)    65536
    float* b4    = b3 + 65536;          // (2,16,16,64)    32768
    float* lf1o  = b4 + 32768;          // (2,16,16,64)    32768
    float* lf2o  = lf1o + 32768;        // (2,16,16,64)    32768
    float* gf1o  = lf2o + 32768;        // (2,8,8,64)       8192
    float* gf2o  = gf1o + 8192;         // (2,4,4,64)       2048
    float* fc1o  = gf2o + 2048;         // (2,256)           512
    float* fc2o  = fc1o + 512;          // (2,128)           256
    float* fc3o  = fc2o + 256;          // (2,64)            128
    float* gt    = fc3o + 128;          // (2,2048,12)     49152
    // repacked weights [k][oc][ic]
    float* wll2T = gt + 49152;          //  1152
    float* wll3T = wll2T + 1152;        //  4608
    float* wll4T = wll3T + 4608;        // 18432
    float* wlf1T = wll4T + 18432;       // 36864
    float* wlf2T = wlf1T + 36864;       // 36864
    float* wgf1T = wlf2T + 36864;       // 36864
    float* wgf2T = wgf1T + 36864;       // 36864
    float* wfc1T = wgf2T + 36864;       // 262144

    float* out = (float*)d_out;
    dim3 blk(256);

    // K1: repack (1695 blocks) + ll1 (128 blocks)
    k1_repack_ll1<<<1695 + 128, blk, 0, stream>>>(
        ll2_w, ll3_w, ll4_w, lf1_w, lf2_w, gf1_w, gf2_w,
        wll2T, wll3T, wll4T, wlf1T, wlf2T, wgf1T, wgf2T,
        fc1_w, wfc1T,
        low_res, ll1_w, ll1_b, b1);
    // K2-K4: trunk (ll4 at G=4)
    conv_nhwc_split<16, 8, 1, true, true><<<cdiv(BS*64*64*16, 256), blk, 0, stream>>>(b1, wll2T, ll2_b, b2, 128, 128, 64, 64, 2);
    conv_nhwc_split<32, 16, 1, true, true><<<cdiv(BS*32*32*32, 256), blk, 0, stream>>>(b2, wll3T, ll3_b, b3, 64, 64, 32, 32, 2);
    conv_nhwc_split<64, 32, 4, true, true><<<cdiv(BS*16*16*64*4, 256), blk, 0, stream>>>(b3, wll4T, ll4_b, b4, 32, 32, 16, 16, 2);
    // K5: lf1 (1024 blocks, G=8) + gf1 (256 blocks, G=8)
    k5_lf1_gf1<<<1024 + 256, blk, 0, stream>>>(b4, wlf1T, lf1_b, lf1o, wgf1T, gf1_b, gf1o);
    // K6: lf2 (1024 blocks, G=8) + gf2 (64 blocks, G=8)
    k6_lf2_gf2<<<1024 + 64, blk, 0, stream>>>(lf1o, wlf2T, lf2o, gf1o, wgf2T, gf2_b, gf2o);
    // K7-K9: FC stack, one wave per output (chip-wide weight fetch)
    fc_wave_kernel<<<cdiv(BS*256*64, 256), blk, 0, stream>>>(gf2o, wfc1T, fc1_b, fc1o, 1024, 256, 1);
    fc_wave_kernel<<<cdiv(BS*128*64, 256), blk, 0, stream>>>(fc1o, fc2_w, fc2_b, fc2o, 256, 128, 1);
    fc_wave_kernel<<<cdiv(BS*64*64, 256),  blk, 0, stream>>>(fc2o, fc3_w, fc3_b, fc3o, 128, 64, 0);
    // K10: fusion + pred -> channel-interleaved grid
    fuse_pred_kernel<<<cdiv(BS*96*256*16, 256), blk, 0, stream>>>(lf2o, fc3o, pred_w, pred_b, gt);
    // K11: per-row slice (y-preblended slab)
    slice_row_kernel<<<BS*HR, blk, 0, stream>>>(high_res, gt, pw_mat, pw_bias, pw_bias_tag,
                                                rho_a, rho_t, out);
}